// Round 2
// baseline (1720.289 us; speedup 1.0000x reference)
//
#include <hip/hip_runtime.h>

#define B_TOT   512
#define T_LEN   512
#define F_IN_D  8
#define H_DIM   128
#define OUT_DIM 7
#define TC      8                 // timesteps per chunk
#define NCHUNK  (T_LEN / TC)      // 64
#define NSUPER  (NCHUNK + 2)      // 66 super-chunks (pipeline fill/drain)
#define BB      2                 // batch rows per block
#define NBLK    (B_TOT / BB)      // 256 blocks -> 1 per CU
#define NTHREADS 512              // 8 waves

typedef __bf16 bf16x8 __attribute__((ext_vector_type(8)));
typedef float  f32x4  __attribute__((ext_vector_type(4)));

// ---- workspace layout (bf16 element offsets) ----
// frag-packed weights: [lyr][mt][kc][lane][8] so a wave loads one coalesced 16B/lane
#define WS_WHH   0                           // [3][32][4][64][8] = 196608 elems
#define WS_WIH12 (3*32*4*64*8)               // [2][32][4][64][8] = 131072 elems
#define WS_WIH0  (WS_WIH12 + 2*32*4*64*8)    // [32][64][8] = 16384 elems (k>=8 zero-pad)
#define WS_BIAS  (WS_WIH0 + 32*64*8)         // float[3][512] combined b_ih+b_hh

struct __align__(16) SharedMem {
  float  xg[3][16][520];      // per-layer per-chunk input projections (no bias)
  float  g[3][2][520];        // raw gate pre-activations for one step, per layer
  __bf16 hist[2][2][2048];    // [boundary][chunk parity][E]; E = r*128 + ((blk^r)<<3) + (k&7)
  __bf16 h[3][2][2][160];     // [lyr][step parity][b][j]; stride 160 avoids b-conflict
  float  z[2][H_DIM];         // fc1 output
  float  bias[3][512];        // combined biases (added in gate phase)
};                            // total 139712 B < 160 KiB

__device__ __forceinline__ float sigf(float x) {
  return __builtin_amdgcn_rcpf(1.f + __expf(-x));
}
__device__ __forceinline__ float tanh_fast(float x) {
  x = fminf(fmaxf(x, -15.f), 15.f);
  float e = __expf(2.f * x);
  return (e - 1.f) * __builtin_amdgcn_rcpf(e + 1.f);
}
__device__ __forceinline__ bf16x8 load8_f32_bf16(const float* p) {
  const f32x4 a = *(const f32x4*)p;
  const f32x4 b = *(const f32x4*)(p + 4);
  bf16x8 r;
  #pragma unroll
  for (int j = 0; j < 4; ++j) { r[j] = (__bf16)a[j]; r[4 + j] = (__bf16)b[j]; }
  return r;
}
__device__ __forceinline__ bf16x8 zero_bf16x8() {
  bf16x8 r;
  #pragma unroll
  for (int j = 0; j < 8; ++j) r[j] = (__bf16)0.f;
  return r;
}

// ---- prep: pack weights into frag order (bf16) + combine biases ----
__global__ void prep_kernel(const float* __restrict__ wih0, const float* __restrict__ whh0,
                            const float* __restrict__ bih0, const float* __restrict__ bhh0,
                            const float* __restrict__ wih1, const float* __restrict__ whh1,
                            const float* __restrict__ bih1, const float* __restrict__ bhh1,
                            const float* __restrict__ wih2, const float* __restrict__ whh2,
                            const float* __restrict__ bih2, const float* __restrict__ bhh2,
                            __bf16* __restrict__ ws)
{
  const float* WHH[3] = {whh0, whh1, whh2};
  const float* WIH[3] = {wih0, wih1, wih2};
  const float* BIH[3] = {bih0, bih1, bih2};
  const float* BHH[3] = {bhh0, bhh1, bhh2};
  const int NWHH = 3 * 32 * 4 * 64;   // frag-lane jobs
  const int NWIH = 2 * 32 * 4 * 64;
  const int NW0  = 32 * 64;
  const int NBIA = 3 * 512;
  const int TOTAL = NWHH + NWIH + NW0 + NBIA;   // 44544
  for (int idx = blockIdx.x * blockDim.x + threadIdx.x; idx < TOTAL;
       idx += gridDim.x * blockDim.x) {
    if (idx < NWHH) {
      const int lyr = idx >> 13, rem = idx & 8191;
      const int mt = rem >> 8, kc = (rem >> 6) & 3, lane = rem & 63;
      const int row = 16 * mt + (lane & 15);
      const int k0  = kc * 32 + (lane >> 4) * 8;
      const float* src = WHH[lyr] + row * H_DIM + k0;
      __bf16* dst = ws + WS_WHH + (size_t)idx * 8;
      #pragma unroll
      for (int j = 0; j < 8; ++j) dst[j] = (__bf16)src[j];
    } else if (idx < NWHH + NWIH) {
      const int i2 = idx - NWHH;
      const int lyr = (i2 >> 13) + 1, rem = i2 & 8191;
      const int mt = rem >> 8, kc = (rem >> 6) & 3, lane = rem & 63;
      const int row = 16 * mt + (lane & 15);
      const int k0  = kc * 32 + (lane >> 4) * 8;
      const float* src = WIH[lyr] + row * H_DIM + k0;
      __bf16* dst = ws + WS_WIH12 + (size_t)i2 * 8;
      #pragma unroll
      for (int j = 0; j < 8; ++j) dst[j] = (__bf16)src[j];
    } else if (idx < NWHH + NWIH + NW0) {
      const int i3 = idx - NWHH - NWIH;
      const int mt = i3 >> 6, lane = i3 & 63;
      const int row = 16 * mt + (lane & 15);
      const int k0  = (lane >> 4) * 8;
      __bf16* dst = ws + WS_WIH0 + (size_t)i3 * 8;
      #pragma unroll
      for (int j = 0; j < 8; ++j) {
        const int k = k0 + j;
        dst[j] = (k < F_IN_D) ? (__bf16)WIH[0][row * F_IN_D + k] : (__bf16)0.f;
      }
    } else {
      const int i4 = idx - NWHH - NWIH - NW0;
      const int lyr = i4 >> 9, gidx = i4 & 511;
      float* fb = (float*)(ws + WS_BIAS);
      fb[i4] = BIH[lyr][gidx] + BHH[lyr][gidx];
    }
  }
}

// R3: 3-layer wavefront pipeline. Super-chunk C runs layer0 chunk C, layer1
// chunk C-1, layer2 chunk C-2 concurrently (layer l active iff l<=C<64+l).
// All layers share each step's MFMA phase / barrier / gate phase / barrier, so
// per-step fixed costs amortize 3x; serial length 1536 steps -> 528 super-steps.
// whh frags (all 3 layers) register-resident (192 VGPR); wih streamed from the
// packed ws each chunk prologue; inter-layer h via XOR-swizzled LDS hist.
// Step parity = s&1 for all layers (TC even). Gate scheme = R1 (LDS g, compact
// threads): R2's in-register gates cost 8x transcendental issue (measured).
__global__ __launch_bounds__(NTHREADS, 2)
void lstm_kernel(const float* __restrict__ x,
                 const float* __restrict__ fc1w, const float* __restrict__ fc1b,
                 const float* __restrict__ fc2w, const float* __restrict__ fc2b,
                 float* __restrict__ out, const __bf16* __restrict__ ws)
{
  __shared__ SharedMem sh;
  const int tid = threadIdx.x;
  const int w   = tid >> 6;   // wave 0..7
  const int l   = tid & 63;   // lane
  const int q   = l >> 4;     // quad 0..3
  const int n16 = l & 15;     // MFMA col / row-within-tile
  const int bg  = blockIdx.x * BB;

  // gate-phase ownership: primary elem (lyr_p, bbp, jp); threads<256 also own L2
  const int lyr_p = tid >> 8;          // waves 0-3 -> L0, waves 4-7 -> L1
  const int bbp   = (tid >> 7) & 1;
  const int jp    = tid & 127;

  // ---- resident whh fragments: 3 layers x 4 tiles x 4 k-chunks ----
  bf16x8 whhf[3][4][4];
  #pragma unroll
  for (int lyr = 0; lyr < 3; ++lyr)
    #pragma unroll
    for (int i = 0; i < 4; ++i)
      #pragma unroll
      for (int kc = 0; kc < 4; ++kc)
        whhf[lyr][i][kc] = *(const bf16x8*)(
            ws + WS_WHH + ((((size_t)lyr * 32 + (w + 8 * i)) * 4 + kc) * 64 + l) * 8);

  // ---- biases -> LDS; zero h state ----
  {
    const float* fb = (const float*)(ws + WS_BIAS);
    #pragma unroll
    for (int lyr = 0; lyr < 3; ++lyr) sh.bias[lyr][tid] = fb[lyr * 512 + tid];
  }
  {
    __bf16* hp = &sh.h[0][0][0][0];
    for (int e = tid; e < 3 * 2 * 2 * 160; e += NTHREADS) hp[e] = (__bf16)0.f;
  }
  float cstP = 0.f;   // cell state, primary elem
  float cstS = 0.f;   // cell state, L2 elem (threads < 256)
  __syncthreads();

  for (int C = 0; C < NSUPER; ++C) {
    // ---------- prologue: xg for each active layer's current chunk ----------
    if (C < NCHUNK) {            // layer 0, input = x
      const int t0 = C * TC;
      const int bb = n16 & 1, trel = n16 >> 1;
      bf16x8 bfrag = zero_bf16x8();
      if (q == 0)
        bfrag = load8_f32_bf16(x + ((size_t)(bg + bb) * T_LEN + t0 + trel) * F_IN_D);
      f32x4 acc[4];
      #pragma unroll
      for (int i = 0; i < 4; ++i) {
        const bf16x8 af = *(const bf16x8*)(
            ws + WS_WIH0 + ((size_t)(w + 8 * i) * 64 + l) * 8);
        f32x4 zc = {0.f, 0.f, 0.f, 0.f};
        acc[i] = __builtin_amdgcn_mfma_f32_16x16x32_bf16(af, bfrag, zc, 0, 0, 0);
      }
      #pragma unroll
      for (int i = 0; i < 4; ++i)
        *(f32x4*)&sh.xg[0][n16][16 * (w + 8 * i) + 4 * q] = acc[i];
    }
    #pragma unroll
    for (int lyr = 1; lyr < 3; ++lyr) {   // layers 1,2: input = hist[lyr-1]
      if (C >= lyr && C - lyr < NCHUNK) {
        const int par = (C - lyr) & 1;
        const __bf16* hb = &sh.hist[lyr - 1][par][0];
        f32x4 acc[4] = {{0.f,0.f,0.f,0.f},{0.f,0.f,0.f,0.f},
                        {0.f,0.f,0.f,0.f},{0.f,0.f,0.f,0.f}};
        #pragma unroll
        for (int kc = 0; kc < 4; ++kc) {
          const int b0 = kc * 4 + q;
          const bf16x8 bfrag = *(const bf16x8*)&hb[n16 * 128 + ((b0 ^ n16) << 3)];
          #pragma unroll
          for (int i = 0; i < 4; ++i) {
            const bf16x8 af = *(const bf16x8*)(
                ws + WS_WIH12 +
                (((((size_t)(lyr - 1)) * 32 + (w + 8 * i)) * 4 + kc) * 64 + l) * 8);
            acc[i] = __builtin_amdgcn_mfma_f32_16x16x32_bf16(af, bfrag, acc[i], 0, 0, 0);
          }
        }
        #pragma unroll
        for (int i = 0; i < 4; ++i)
          *(f32x4*)&sh.xg[lyr][n16][16 * (w + 8 * i) + 4 * q] = acc[i];
      }
    }
    __syncthreads();

    // ---------- TC steps; all active layers advance one t per step ----------
    for (int s = 0; s < TC; ++s) {
      const int cur = s & 1, nxt = cur ^ 1;

      // MFMA phase (8 waves, up to 3 layers sequentially; chains independent)
      #pragma unroll
      for (int lyr = 0; lyr < 3; ++lyr) {
        if (C >= lyr && C - lyr < NCHUNK) {
          f32x4 acc[4];
          #pragma unroll
          for (int i = 0; i < 4; ++i)
            acc[i] = *(const f32x4*)&sh.xg[lyr][2 * s + (l & 1)][16 * (w + 8 * i) + 4 * q];
          #pragma unroll
          for (int kc = 0; kc < 4; ++kc) {
            const bf16x8 bfrag =
                *(const bf16x8*)&sh.h[lyr][cur][n16 & 1][kc * 32 + q * 8];
            #pragma unroll
            for (int i = 0; i < 4; ++i)
              acc[i] = __builtin_amdgcn_mfma_f32_16x16x32_bf16(
                  whhf[lyr][i][kc], bfrag, acc[i], 0, 0, 0);
          }
          if (n16 < 2) {
            #pragma unroll
            for (int i = 0; i < 4; ++i)
              *(f32x4*)&sh.g[lyr][n16][16 * (w + 8 * i) + 4 * q] = acc[i];
          }
        }
      }
      __syncthreads();

      // gate phase: 768 elems spread as primary (all threads) + L2 (threads<256)
      if (C >= lyr_p && C - lyr_p < NCHUNK) {
        const float gi = sh.g[lyr_p][bbp][jp]            + sh.bias[lyr_p][jp];
        const float gf = sh.g[lyr_p][bbp][H_DIM + jp]    + sh.bias[lyr_p][H_DIM + jp];
        const float gg = sh.g[lyr_p][bbp][2*H_DIM + jp]  + sh.bias[lyr_p][2*H_DIM + jp];
        const float go = sh.g[lyr_p][bbp][3*H_DIM + jp]  + sh.bias[lyr_p][3*H_DIM + jp];
        cstP = sigf(gf) * cstP + sigf(gi) * tanh_fast(gg);
        const float hv = sigf(go) * tanh_fast(cstP);
        const __bf16 hbv = (__bf16)hv;
        sh.h[lyr_p][nxt][bbp][jp] = hbv;       // broadcast for t+1
        // boundary hist (lyr_p is always 0 or 1): swizzled for prologue read
        const int par = (C - lyr_p) & 1;
        const int r = 2 * s + bbp;
        sh.hist[lyr_p][par][r * 128 + (((jp >> 3) ^ r) << 3) + (jp & 7)] = hbv;
      }
      if (tid < 256 && C >= 2 && C - 2 < NCHUNK) {
        const float gi = sh.g[2][bbp][jp]            + sh.bias[2][jp];
        const float gf = sh.g[2][bbp][H_DIM + jp]    + sh.bias[2][H_DIM + jp];
        const float gg = sh.g[2][bbp][2*H_DIM + jp]  + sh.bias[2][2*H_DIM + jp];
        const float go = sh.g[2][bbp][3*H_DIM + jp]  + sh.bias[2][3*H_DIM + jp];
        cstS = sigf(gf) * cstS + sigf(gi) * tanh_fast(gg);
        const float hv = sigf(go) * tanh_fast(cstS);
        sh.h[2][nxt][bbp][jp] = (__bf16)hv;    // no hist for the last layer
      }
      __syncthreads();
    }
  }

  // ---- FC head: layer2 final h (t=511 at C=65,s=7 wrote parity 0) ----
  if (tid < 2 * H_DIM) {
    const int bb = tid >> 7, i = tid & 127;
    float a = fc1b[i];
    #pragma unroll 8
    for (int k = 0; k < H_DIM; ++k)
      a += (float)sh.h[2][0][bb][k] * fc1w[i * H_DIM + k];
    sh.z[bb][i] = fmaxf(a, 0.f);
  }
  __syncthreads();
  if (tid < BB * OUT_DIM) {
    const int bb = tid / OUT_DIM, o = tid % OUT_DIM;
    float a = fc2b[o];
    for (int k = 0; k < H_DIM; ++k)
      a += sh.z[bb][k] * fc2w[o * H_DIM + k];
    out[(size_t)(bg + bb) * OUT_DIM + o] = a;
  }
}

extern "C" void kernel_launch(void* const* d_in, const int* in_sizes, int n_in,
                              void* d_out, int out_size, void* d_ws, size_t ws_size,
                              hipStream_t stream) {
  const float* x    = (const float*)d_in[0];
  const float* wih0 = (const float*)d_in[1];
  const float* whh0 = (const float*)d_in[2];
  const float* bih0 = (const float*)d_in[3];
  const float* bhh0 = (const float*)d_in[4];
  const float* wih1 = (const float*)d_in[5];
  const float* whh1 = (const float*)d_in[6];
  const float* bih1 = (const float*)d_in[7];
  const float* bhh1 = (const float*)d_in[8];
  const float* wih2 = (const float*)d_in[9];
  const float* whh2 = (const float*)d_in[10];
  const float* bih2 = (const float*)d_in[11];
  const float* bhh2 = (const float*)d_in[12];
  const float* fc1w = (const float*)d_in[13];
  const float* fc1b = (const float*)d_in[14];
  const float* fc2w = (const float*)d_in[15];
  const float* fc2b = (const float*)d_in[16];
  float* out  = (float*)d_out;
  __bf16* ws  = (__bf16*)d_ws;

  prep_kernel<<<dim3(174), dim3(256), 0, stream>>>(
      wih0, whh0, bih0, bhh0, wih1, whh1, bih1, bhh1,
      wih2, whh2, bih2, bhh2, ws);
  lstm_kernel<<<dim3(NBLK), dim3(NTHREADS), 0, stream>>>(
      x, fc1w, fc1b, fc2w, fc2b, out, (const __bf16*)ws);
}

// Round 4
// 1384.623 us; speedup vs baseline: 1.2424x; 1.2424x over previous
//
#include <hip/hip_runtime.h>

#define B_TOT   512
#define T_LEN   512
#define F_IN_D  8
#define H_DIM   128
#define OUT_DIM 7
#define TC      4                 // timesteps per chunk (xg register granularity)
#define NCHUNK  (T_LEN / TC)      // 128
#define RSLOT   32                // ring slots per layer boundary
#define BBATCH  16                // batch rows per block (full MFMA N)
#define NGRP    (B_TOT / BBATCH)  // 32 groups
#define NTHREADS 512              // 8 waves
#define SPIN_LIMIT (1 << 18)      // ~50 ms cap per wait: fail-visible, never hang

typedef __bf16 bf16x8 __attribute__((ext_vector_type(8)));
typedef __bf16 bf16x4 __attribute__((ext_vector_type(4)));
typedef float  f32x4  __attribute__((ext_vector_type(4)));

// ---- workspace layout (bf16 element offsets) ----
#define WS_WHH   0                     // [3][32][4][64][8] = 196608
#define WS_WIH12 196608                // [2][32][4][64][8] = 131072
#define WS_WIH0  327680                // [32][64][8] = 16384 (k>=8 zero-padded)
#define WS_BIAS  344064                // float[3][512] combined b_ih+b_hh
#define WS_FLAGS 347136                // int[2][32] flags, then int[2][32] consumed
#define WS_BUF   347648                // [2][32] pair ring buffers
#define CH_ELEMS   (TC * BBATCH * H_DIM)   // 8192 bf16 per chunk
#define PAIR_ELEMS (RSLOT * CH_ELEMS)      // 262144 (512 KiB per pair)

// h layout [kgroup][batch][8]: element (batch b, hdim k) at [k>>3][b][k&7].
// Step B-frag read (lane q,n16 needs k in [kc*32+q*8,+8), col n16) is then a
// CONTIGUOUS 1KB wave read -> zero bank conflicts. Ring slots use the same
// layout so flush is a verbatim 16KB copy and consumer reads are contiguous.
struct __align__(16) SharedMem {
  __bf16 h[2][16][16][8];     // [step parity][kgroup][batch][k&7]  (8 KB)
  __bf16 hist[TC][16][16][8]; // chunk h history, ring-slot layout  (16 KB)
  float  z[16][H_DIM];        // fc1 output (layer-2 blocks only)   (8 KB)
};

__device__ __forceinline__ float sigf(float x) {
  return __builtin_amdgcn_rcpf(1.f + __expf(-x));
}
__device__ __forceinline__ float tanh_fast(float x) {
  x = fminf(fmaxf(x, -15.f), 15.f);
  float e = __expf(2.f * x);
  return (e - 1.f) * __builtin_amdgcn_rcpf(e + 1.f);
}
__device__ __forceinline__ bf16x8 load8_f32_bf16(const float* p) {
  const f32x4 a = *(const f32x4*)p;
  const f32x4 b = *(const f32x4*)(p + 4);
  bf16x8 r;
  #pragma unroll
  for (int j = 0; j < 4; ++j) { r[j] = (__bf16)a[j]; r[4 + j] = (__bf16)b[j]; }
  return r;
}
__device__ __forceinline__ bf16x8 zero_bf16x8() {
  bf16x8 r;
  #pragma unroll
  for (int j = 0; j < 8; ++j) r[j] = (__bf16)0.f;
  return r;
}
__device__ __forceinline__ int aload(int* p) {
  return __hip_atomic_load(p, __ATOMIC_ACQUIRE, __HIP_MEMORY_SCOPE_AGENT);
}
__device__ __forceinline__ void astore(int* p, int v) {
  __hip_atomic_store(p, v, __ATOMIC_RELEASE, __HIP_MEMORY_SCOPE_AGENT);
}

// ---- prep: pack weights into frag order (bf16), combine biases, zero flags ----
__global__ void prep_kernel(const float* __restrict__ wih0, const float* __restrict__ whh0,
                            const float* __restrict__ bih0, const float* __restrict__ bhh0,
                            const float* __restrict__ wih1, const float* __restrict__ whh1,
                            const float* __restrict__ bih1, const float* __restrict__ bhh1,
                            const float* __restrict__ wih2, const float* __restrict__ whh2,
                            const float* __restrict__ bih2, const float* __restrict__ bhh2,
                            __bf16* __restrict__ ws)
{
  const float* WHH[3] = {whh0, whh1, whh2};
  const float* WIH[3] = {wih0, wih1, wih2};
  const float* BIH[3] = {bih0, bih1, bih2};
  const float* BHH[3] = {bhh0, bhh1, bhh2};
  const int NWHH = 3 * 32 * 4 * 64;   // 24576
  const int NWIH = 2 * 32 * 4 * 64;   // 16384
  const int NW0  = 32 * 64;           // 2048
  const int NBIA = 3 * 512;           // 1536
  const int NFLG = 128;               // flags + consumed
  const int TOTAL = NWHH + NWIH + NW0 + NBIA + NFLG;
  for (int idx = blockIdx.x * blockDim.x + threadIdx.x; idx < TOTAL;
       idx += gridDim.x * blockDim.x) {
    if (idx < NWHH) {
      const int lyr = idx >> 13, rem = idx & 8191;
      const int mt = rem >> 8, kc = (rem >> 6) & 3, lane = rem & 63;
      const int row = 16 * mt + (lane & 15);
      const int k0  = kc * 32 + (lane >> 4) * 8;
      const float* src = WHH[lyr] + row * H_DIM + k0;
      __bf16* dst = ws + WS_WHH + (size_t)idx * 8;
      #pragma unroll
      for (int j = 0; j < 8; ++j) dst[j] = (__bf16)src[j];
    } else if (idx < NWHH + NWIH) {
      const int i2 = idx - NWHH;
      const int lyr = (i2 >> 13) + 1, rem = i2 & 8191;
      const int mt = rem >> 8, kc = (rem >> 6) & 3, lane = rem & 63;
      const int row = 16 * mt + (lane & 15);
      const int k0  = kc * 32 + (lane >> 4) * 8;
      const float* src = WIH[lyr] + row * H_DIM + k0;
      __bf16* dst = ws + WS_WIH12 + (size_t)i2 * 8;
      #pragma unroll
      for (int j = 0; j < 8; ++j) dst[j] = (__bf16)src[j];
    } else if (idx < NWHH + NWIH + NW0) {
      const int i3 = idx - NWHH - NWIH;
      const int mt = i3 >> 6, lane = i3 & 63;
      const int row = 16 * mt + (lane & 15);
      const int k0  = (lane >> 4) * 8;
      __bf16* dst = ws + WS_WIH0 + (size_t)i3 * 8;
      #pragma unroll
      for (int j = 0; j < 8; ++j) {
        const int k = k0 + j;
        dst[j] = (k < F_IN_D) ? (__bf16)WIH[0][row * F_IN_D + k] : (__bf16)0.f;
      }
    } else if (idx < NWHH + NWIH + NW0 + NBIA) {
      const int i4 = idx - NWHH - NWIH - NW0;
      float* fb = (float*)(ws + WS_BIAS);
      fb[i4] = BIH[i4 >> 9][i4 & 511] + BHH[i4 >> 9][i4 & 511];
    } else {
      const int i5 = idx - NWHH - NWIH - NW0 - NBIA;
      ((int*)(ws + WS_FLAGS))[i5] = 0;
    }
  }
}

// R5: cross-block layer pipeline (hardened R4). Block (lyr,g) runs layer lyr
// for batch rows [16g,16g+16); N=16 MFMA cols all live. Wave w owns M-tiles
// {w,w+8,w+16,w+24} = gates i,f,g,o for h rows [16w,16w+16): acc[k][r] = gate
// k of h-row 16w+4q+r, batch col n16 -> gates fully in-register (zero waste at
// BBATCH=16; this was R2's loss at BB=2), ONE barrier per step. xg for TC=4
// steps lives in 64 VGPRs. Layers hand off chunks via a 32-slot global ring
// with acquire/release flags; flag semantics: flags=v => chunks [0,v) flushed
// & visible; cons=v => consumer finished reading chunks [0,v). Flush of chunk
// c-1 is issued BEFORE prologue(c) and drained by the post-prologue barrier
// (overlap). All spins are BOUNDED: a protocol stall produces a fast wrong
// answer (passed:false + counters) instead of a container hang.
__global__ __launch_bounds__(NTHREADS, 2)
void lstm_kernel(const float* __restrict__ x,
                 const float* __restrict__ fc1w, const float* __restrict__ fc1b,
                 const float* __restrict__ fc2w, const float* __restrict__ fc2b,
                 float* __restrict__ out, __bf16* __restrict__ ws)
{
  __shared__ SharedMem sh;
  const int tid = threadIdx.x;
  const int w   = tid >> 6;   // wave 0..7
  const int l   = tid & 63;   // lane
  const int q   = l >> 4;     // quad 0..3
  const int n16 = l & 15;     // MFMA col = batch row within group
  const int lyr = blockIdx.x >> 5;   // 0..2
  const int g   = blockIdx.x & 31;   // batch group
  const int bg  = g * BBATCH;
  const int kg_w = 2 * w + (q >> 1); // kgroup this thread's h-rows land in
  const int sub  = (q & 1) * 4;      // sub-offset within the 8-elem kgroup

  int* flags = (int*)(ws + WS_FLAGS);
  int* cons  = flags + 64;
  const int myidx = (lyr < 2) ? lyr * NGRP + g : 0;
  const int upidx = (lyr > 0) ? (lyr - 1) * NGRP + g : 0;
  int* flag_my = &flags[myidx];
  int* flag_up = &flags[upidx];
  int* cons_my = &cons[myidx];
  int* cons_up = &cons[upidx];
  __bf16*       mybuf = ws + WS_BUF + (size_t)myidx * PAIR_ELEMS;
  const __bf16* upbuf = ws + WS_BUF + (size_t)upidx * PAIR_ELEMS;

  // ---- resident whh fragments + combined bias ----
  bf16x8 whhf[4][4];
  f32x4  biasv[4];
  #pragma unroll
  for (int i = 0; i < 4; ++i) {
    #pragma unroll
    for (int kc = 0; kc < 4; ++kc)
      whhf[i][kc] = *(const bf16x8*)(
          ws + WS_WHH + ((((size_t)lyr * 32 + (w + 8 * i)) * 4 + kc) * 64 + l) * 8);
    const float* fb = (const float*)(ws + WS_BIAS) + lyr * 512 + 16 * (w + 8 * i) + 4 * q;
    biasv[i] = *(const f32x4*)fb;
  }
  bf16x8 wih0f[4];
  if (lyr == 0) {
    #pragma unroll
    for (int i = 0; i < 4; ++i)
      wih0f[i] = *(const bf16x8*)(ws + WS_WIH0 + ((size_t)(w + 8 * i) * 64 + l) * 8);
  }

  // ---- zero initial h (parity 0 read at t=0) ----
  for (int e = tid; e < 2 * 16 * 16 * 8; e += NTHREADS)
    (&sh.h[0][0][0][0])[e] = (__bf16)0.f;
  f32x4 cst = {0.f, 0.f, 0.f, 0.f};   // cell state: rows 16w+4q+0..3, col n16
  __syncthreads();

  for (int c = 0; c < NCHUNK; ++c) {
    // ---- A) consumer: wait until upstream chunk c is flushed & visible ----
    if (lyr > 0) {
      if (tid == 0) {
        for (int it = 0; it < SPIN_LIMIT && aload(flag_up) < c + 1; ++it)
          __builtin_amdgcn_s_sleep(8);
      }
      __syncthreads();
    }

    // ---- B) producer: issue flush of hist(c-1) -> ring (drained at C's barrier) ----
    if (lyr < 2 && c > 0) {
      const int m = c - 1;
      if (tid == 0 && m >= RSLOT) {   // slot reuse: consumer must be done with m-32
        for (int it = 0; it < SPIN_LIMIT && aload(cons_my) < m - RSLOT + 1; ++it)
          __builtin_amdgcn_s_sleep(8);
      }
      __syncthreads();                // all threads know the slot is free
      __bf16* dst = mybuf + (size_t)(m % RSLOT) * CH_ELEMS;
      const __bf16* hsrc = &sh.hist[0][0][0][0];
      #pragma unroll
      for (int it = 0; it < 2; ++it) {
        const int j = tid + it * NTHREADS;     // 1024 bf16x8 jobs, verbatim copy
        *(bf16x8*)(dst + j * 8) = *(const bf16x8*)(hsrc + j * 8);
      }
    }

    // ---- C) prologue: xg(c) into registers (C-init layout) ----
    f32x4 xg[TC][4];
    #pragma unroll
    for (int s = 0; s < TC; ++s)
      #pragma unroll
      for (int i = 0; i < 4; ++i) xg[s][i] = biasv[i];

    if (lyr == 0) {
      #pragma unroll
      for (int s = 0; s < TC; ++s) {
        bf16x8 bfrag = zero_bf16x8();
        if (q == 0)      // k = q*8+j < 8 only in quad 0; weights zero-padded past 8
          bfrag = load8_f32_bf16(x + ((size_t)(bg + n16) * T_LEN + c * TC + s) * F_IN_D);
        #pragma unroll
        for (int i = 0; i < 4; ++i)
          xg[s][i] = __builtin_amdgcn_mfma_f32_16x16x32_bf16(wih0f[i], bfrag, xg[s][i], 0, 0, 0);
      }
    } else {
      const __bf16* src = upbuf + (size_t)(c % RSLOT) * CH_ELEMS;
      #pragma unroll
      for (int kc = 0; kc < 4; ++kc) {
        bf16x8 wf[4];
        #pragma unroll
        for (int i = 0; i < 4; ++i)
          wf[i] = *(const bf16x8*)(ws + WS_WIH12 +
              ((((size_t)(lyr - 1) * 32 + (w + 8 * i)) * 4 + kc) * 64 + l) * 8);
        #pragma unroll
        for (int s = 0; s < TC; ++s) {
          const bf16x8 bfrag = *(const bf16x8*)(
              src + (((size_t)s * 16 + kc * 4 + q) * 16 + n16) * 8);
          #pragma unroll
          for (int i = 0; i < 4; ++i)
            xg[s][i] = __builtin_amdgcn_mfma_f32_16x16x32_bf16(wf[i], bfrag, xg[s][i], 0, 0, 0);
        }
      }
    }

    // barrier drains: flush stores (vmcnt), upbuf/x reads (vmcnt), hist ds_reads
    // (lgkmcnt) -- compiler emits full waitcnt before s_barrier.
    __syncthreads();
    if (lyr < 2 && c > 0 && tid == 0) { __threadfence(); astore(flag_my, c); }
    if (lyr > 0 && tid == 0) astore(cons_up, c + 1);   // slot c reads are drained

    // ---- D) TC recurrence steps: MFMA + in-register gates, ONE barrier ----
    #pragma unroll
    for (int s = 0; s < TC; ++s) {
      const int cur = s & 1, nxt = cur ^ 1;
      f32x4 acc[4];
      #pragma unroll
      for (int k = 0; k < 4; ++k) acc[k] = xg[s][k];
      #pragma unroll
      for (int kc = 0; kc < 4; ++kc) {
        // contiguous 1KB wave read: lane (q,n16) -> h[cur][kc*4+q][n16][0..8)
        const bf16x8 bfrag = *(const bf16x8*)&sh.h[cur][kc * 4 + q][n16][0];
        #pragma unroll
        for (int k = 0; k < 4; ++k)
          acc[k] = __builtin_amdgcn_mfma_f32_16x16x32_bf16(whhf[k][kc], bfrag, acc[k], 0, 0, 0);
      }
      // in-register gates: acc[0..3][r] = i,f,g,o for j=16w+4q+r, batch n16
      bf16x4 hb;
      #pragma unroll
      for (int r = 0; r < 4; ++r) {
        const float gi = sigf(acc[0][r]);
        const float gf = sigf(acc[1][r]);
        const float gg = tanh_fast(acc[2][r]);
        const float go = sigf(acc[3][r]);
        cst[r] = gf * cst[r] + gi * gg;
        hb[r]  = (__bf16)(go * tanh_fast(cst[r]));
      }
      *(bf16x4*)&sh.h[nxt][kg_w][n16][sub] = hb;
      if (lyr < 2) *(bf16x4*)&sh.hist[s][kg_w][n16][sub] = hb;
      __syncthreads();
    }
  }

  // ---- final flush of hist(NCHUNK-1) + terminal flag ----
  if (lyr < 2) {
    const int m = NCHUNK - 1;
    if (tid == 0) {
      for (int it = 0; it < SPIN_LIMIT && aload(cons_my) < m - RSLOT + 1; ++it)
        __builtin_amdgcn_s_sleep(8);
    }
    __syncthreads();
    __bf16* dst = mybuf + (size_t)(m % RSLOT) * CH_ELEMS;
    const __bf16* hsrc = &sh.hist[0][0][0][0];
    #pragma unroll
    for (int it = 0; it < 2; ++it) {
      const int j = tid + it * NTHREADS;
      *(bf16x8*)(dst + j * 8) = *(const bf16x8*)(hsrc + j * 8);
    }
    __syncthreads();
    if (tid == 0) { __threadfence(); astore(flag_my, NCHUNK); }
  }

  // ---- FC head: layer-2 blocks; t=511 (s=3) wrote parity 0 ----
  if (lyr == 2) {
    for (int j = tid; j < BBATCH * H_DIM; j += NTHREADS) {
      const int b = j >> 7, i = j & 127;
      float a = fc1b[i];
      #pragma unroll 8
      for (int k = 0; k < H_DIM; ++k)
        a += (float)sh.h[0][k >> 3][b][k & 7] * fc1w[i * H_DIM + k];
      sh.z[b][i] = fmaxf(a, 0.f);
    }
    __syncthreads();
    if (tid < BBATCH * OUT_DIM) {
      const int b = tid / OUT_DIM, o = tid % OUT_DIM;
      float a = fc2b[o];
      for (int k = 0; k < H_DIM; ++k)
        a += sh.z[b][k] * fc2w[o * H_DIM + k];
      out[(size_t)(bg + b) * OUT_DIM + o] = a;
    }
  }
}

extern "C" void kernel_launch(void* const* d_in, const int* in_sizes, int n_in,
                              void* d_out, int out_size, void* d_ws, size_t ws_size,
                              hipStream_t stream) {
  const float* x    = (const float*)d_in[0];
  const float* wih0 = (const float*)d_in[1];
  const float* whh0 = (const float*)d_in[2];
  const float* bih0 = (const float*)d_in[3];
  const float* bhh0 = (const float*)d_in[4];
  const float* wih1 = (const float*)d_in[5];
  const float* whh1 = (const float*)d_in[6];
  const float* bih1 = (const float*)d_in[7];
  const float* bhh1 = (const float*)d_in[8];
  const float* wih2 = (const float*)d_in[9];
  const float* whh2 = (const float*)d_in[10];
  const float* bih2 = (const float*)d_in[11];
  const float* bhh2 = (const float*)d_in[12];
  const float* fc1w = (const float*)d_in[13];
  const float* fc1b = (const float*)d_in[14];
  const float* fc2w = (const float*)d_in[15];
  const float* fc2b = (const float*)d_in[16];
  float* out  = (float*)d_out;
  __bf16* ws  = (__bf16*)d_ws;   // ~33.7 MB used (weights + flags + 32 MB ring)

  prep_kernel<<<dim3(175), dim3(256), 0, stream>>>(
      wih0, whh0, bih0, bhh0, wih1, whh1, bih1, bhh1,
      wih2, whh2, bih2, bhh2, ws);
  lstm_kernel<<<dim3(3 * NGRP), dim3(NTHREADS), 0, stream>>>(
      x, fc1w, fc1b, fc2w, fc2b, out, ws);
}

// Round 5
// 1163.987 us; speedup vs baseline: 1.4779x; 1.1896x over previous
//
#include <hip/hip_runtime.h>

#define B_TOT   512
#define T_LEN   512
#define F_IN_D  8
#define H_DIM   128
#define OUT_DIM 7
#define TC      4                 // timesteps per chunk (xg register granularity)
#define NCHUNK  (T_LEN / TC)      // 128
#define RSLOT   32                // ring slots per layer boundary
#define BBATCH  16                // batch rows per block (full MFMA N)
#define NGRP    (B_TOT / BBATCH)  // 32 groups
#define NTHREADS 512              // 8 waves
#define SPIN_LIMIT (1 << 18)      // bounded waits: fail-visible, never hang

typedef __bf16 bf16x8 __attribute__((ext_vector_type(8)));
typedef __bf16 bf16x4 __attribute__((ext_vector_type(4)));
typedef float  f32x4  __attribute__((ext_vector_type(4)));
typedef unsigned long long u64;

// ---- workspace layout (bf16 element offsets) ----
#define WS_WHH   0                     // [3][32][4][64][8] = 196608
#define WS_WIH12 196608                // [2][32][4][64][8] = 131072
#define WS_WIH0  327680                // [32][64][8] = 16384 (k>=8 zero-padded)
#define WS_BIAS  344064                // float[3][512] combined b_ih+b_hh
#define WS_FLAGS 347136                // int[2][32] flags, then int[2][32] consumed
#define WS_BUF   347648                // [2][32] pair ring buffers
#define CH_ELEMS   (TC * BBATCH * H_DIM)   // 8192 bf16 per chunk (16 KB)
#define CH_U64     (CH_ELEMS / 4)          // 2048 u64 per chunk
#define PAIR_ELEMS (RSLOT * CH_ELEMS)      // 262144 (512 KiB per pair)

// h layout [kgroup][batch][8]: element (batch b, hdim k) at [k>>3][b][k&7].
// Step B-frag read (lane q,n16 needs k in [kc*32+q*8,+8), col n16) is a
// CONTIGUOUS 1KB wave read -> zero bank conflicts. Ring slots use the same
// layout so flush is a verbatim 16KB copy and consumer reads are contiguous.
struct __align__(16) SharedMem {
  __bf16 h[2][16][16][8];     // [step parity][kgroup][batch][k&7]  (8 KB)
  __bf16 hist[TC][16][16][8]; // chunk h history, ring-slot layout  (16 KB)
  float  z[16][H_DIM];        // fc1 output (layer-2 blocks only)   (8 KB)
};

__device__ __forceinline__ float sigf(float x) {
  return __builtin_amdgcn_rcpf(1.f + __expf(-x));
}
__device__ __forceinline__ float tanh_fast(float x) {
  x = fminf(fmaxf(x, -15.f), 15.f);
  float e = __expf(2.f * x);
  return (e - 1.f) * __builtin_amdgcn_rcpf(e + 1.f);
}
__device__ __forceinline__ bf16x8 load8_f32_bf16(const float* p) {
  const f32x4 a = *(const f32x4*)p;
  const f32x4 b = *(const f32x4*)(p + 4);
  bf16x8 r;
  #pragma unroll
  for (int j = 0; j < 4; ++j) { r[j] = (__bf16)a[j]; r[4 + j] = (__bf16)b[j]; }
  return r;
}
__device__ __forceinline__ bf16x8 zero_bf16x8() {
  bf16x8 r;
  #pragma unroll
  for (int j = 0; j < 8; ++j) r[j] = (__bf16)0.f;
  return r;
}
// R6: ALL cross-block traffic is agent-scope RELAXED atomics -> coherent at
// the Infinity Cache by construction. No acquire/release, no __threadfence:
// eliminates the buffer_wbl2 / buffer_inv cache-maintenance ops that cost
// R5 ~5us per chunk. Ordering: the post-prologue __syncthreads drains each
// thread's vmcnt(0) (compiler-guaranteed before s_barrier), so data atomics
// have completed at the coherence point before the flag atomic is issued.
__device__ __forceinline__ int afl_load(int* p) {
  return __hip_atomic_load(p, __ATOMIC_RELAXED, __HIP_MEMORY_SCOPE_AGENT);
}
__device__ __forceinline__ void afl_store(int* p, int v) {
  __hip_atomic_store(p, v, __ATOMIC_RELAXED, __HIP_MEMORY_SCOPE_AGENT);
}
__device__ __forceinline__ u64 adat_load(const u64* p) {
  return __hip_atomic_load(p, __ATOMIC_RELAXED, __HIP_MEMORY_SCOPE_AGENT);
}
__device__ __forceinline__ void adat_store(u64* p, u64 v) {
  __hip_atomic_store(p, v, __ATOMIC_RELAXED, __HIP_MEMORY_SCOPE_AGENT);
}

// ---- prep: pack weights into frag order (bf16), combine biases, zero flags ----
__global__ void prep_kernel(const float* __restrict__ wih0, const float* __restrict__ whh0,
                            const float* __restrict__ bih0, const float* __restrict__ bhh0,
                            const float* __restrict__ wih1, const float* __restrict__ whh1,
                            const float* __restrict__ bih1, const float* __restrict__ bhh1,
                            const float* __restrict__ wih2, const float* __restrict__ whh2,
                            const float* __restrict__ bih2, const float* __restrict__ bhh2,
                            __bf16* __restrict__ ws)
{
  const float* WHH[3] = {whh0, whh1, whh2};
  const float* WIH[3] = {wih0, wih1, wih2};
  const float* BIH[3] = {bih0, bih1, bih2};
  const float* BHH[3] = {bhh0, bhh1, bhh2};
  const int NWHH = 3 * 32 * 4 * 64;   // 24576
  const int NWIH = 2 * 32 * 4 * 64;   // 16384
  const int NW0  = 32 * 64;           // 2048
  const int NBIA = 3 * 512;           // 1536
  const int NFLG = 128;               // flags + consumed
  const int TOTAL = NWHH + NWIH + NW0 + NBIA + NFLG;
  for (int idx = blockIdx.x * blockDim.x + threadIdx.x; idx < TOTAL;
       idx += gridDim.x * blockDim.x) {
    if (idx < NWHH) {
      const int lyr = idx >> 13, rem = idx & 8191;
      const int mt = rem >> 8, kc = (rem >> 6) & 3, lane = rem & 63;
      const int row = 16 * mt + (lane & 15);
      const int k0  = kc * 32 + (lane >> 4) * 8;
      const float* src = WHH[lyr] + row * H_DIM + k0;
      __bf16* dst = ws + WS_WHH + (size_t)idx * 8;
      #pragma unroll
      for (int j = 0; j < 8; ++j) dst[j] = (__bf16)src[j];
    } else if (idx < NWHH + NWIH) {
      const int i2 = idx - NWHH;
      const int lyr = (i2 >> 13) + 1, rem = i2 & 8191;
      const int mt = rem >> 8, kc = (rem >> 6) & 3, lane = rem & 63;
      const int row = 16 * mt + (lane & 15);
      const int k0  = kc * 32 + (lane >> 4) * 8;
      const float* src = WIH[lyr] + row * H_DIM + k0;
      __bf16* dst = ws + WS_WIH12 + (size_t)i2 * 8;
      #pragma unroll
      for (int j = 0; j < 8; ++j) dst[j] = (__bf16)src[j];
    } else if (idx < NWHH + NWIH + NW0) {
      const int i3 = idx - NWHH - NWIH;
      const int mt = i3 >> 6, lane = i3 & 63;
      const int row = 16 * mt + (lane & 15);
      const int k0  = (lane >> 4) * 8;
      __bf16* dst = ws + WS_WIH0 + (size_t)i3 * 8;
      #pragma unroll
      for (int j = 0; j < 8; ++j) {
        const int k = k0 + j;
        dst[j] = (k < F_IN_D) ? (__bf16)WIH[0][row * F_IN_D + k] : (__bf16)0.f;
      }
    } else if (idx < NWHH + NWIH + NW0 + NBIA) {
      const int i4 = idx - NWHH - NWIH - NW0;
      float* fb = (float*)(ws + WS_BIAS);
      fb[i4] = BIH[i4 >> 9][i4 & 511] + BHH[i4 >> 9][i4 & 511];
    } else {
      const int i5 = idx - NWHH - NWIH - NW0 - NBIA;
      ((int*)(ws + WS_FLAGS))[i5] = 0;
    }
  }
}

// R6: cross-block layer pipeline, fence-free handshake. Block (lyr,g) runs
// layer lyr for batch rows [16g,16g+16); N=16 MFMA cols all live. Wave w owns
// M-tiles {w,w+8,w+16,w+24} = gates i,f,g,o for h rows [16w,16w+16):
// acc[k][r] = gate k of h-row 16w+4q+r, batch col n16 -> gates fully
// in-register, ONE barrier per step. Layers hand off TC-step chunks via a
// 32-slot ring; flags=v => chunks [0,v) flushed & at coherence point;
// cons=v => consumer finished reading chunks [0,v). All spins BOUNDED.
__global__ __launch_bounds__(NTHREADS, 2)
void lstm_kernel(const float* __restrict__ x,
                 const float* __restrict__ fc1w, const float* __restrict__ fc1b,
                 const float* __restrict__ fc2w, const float* __restrict__ fc2b,
                 float* __restrict__ out, __bf16* __restrict__ ws)
{
  __shared__ SharedMem sh;
  const int tid = threadIdx.x;
  const int w   = tid >> 6;   // wave 0..7
  const int l   = tid & 63;   // lane
  const int q   = l >> 4;     // quad 0..3
  const int n16 = l & 15;     // MFMA col = batch row within group
  const int lyr = blockIdx.x >> 5;   // 0..2
  const int g   = blockIdx.x & 31;   // batch group
  const int bg  = g * BBATCH;
  const int kg_w = 2 * w + (q >> 1); // kgroup this thread's h-rows land in
  const int sub  = (q & 1) * 4;      // sub-offset within the 8-elem kgroup

  int* flags = (int*)(ws + WS_FLAGS);
  int* cons  = flags + 64;
  const int myidx = (lyr < 2) ? lyr * NGRP + g : 0;
  const int upidx = (lyr > 0) ? (lyr - 1) * NGRP + g : 0;
  int* flag_my = &flags[myidx];
  int* flag_up = &flags[upidx];
  int* cons_my = &cons[myidx];
  int* cons_up = &cons[upidx];
  u64*       mybuf = (u64*)(ws + WS_BUF + (size_t)myidx * PAIR_ELEMS);
  const u64* upbuf = (const u64*)(ws + WS_BUF + (size_t)upidx * PAIR_ELEMS);

  // ---- resident whh fragments + combined bias ----
  bf16x8 whhf[4][4];
  f32x4  biasv[4];
  #pragma unroll
  for (int i = 0; i < 4; ++i) {
    #pragma unroll
    for (int kc = 0; kc < 4; ++kc)
      whhf[i][kc] = *(const bf16x8*)(
          ws + WS_WHH + ((((size_t)lyr * 32 + (w + 8 * i)) * 4 + kc) * 64 + l) * 8);
    const float* fb = (const float*)(ws + WS_BIAS) + lyr * 512 + 16 * (w + 8 * i) + 4 * q;
    biasv[i] = *(const f32x4*)fb;
  }
  bf16x8 wih0f[4];
  if (lyr == 0) {
    #pragma unroll
    for (int i = 0; i < 4; ++i)
      wih0f[i] = *(const bf16x8*)(ws + WS_WIH0 + ((size_t)(w + 8 * i) * 64 + l) * 8);
  }

  // ---- zero initial h (parity 0 read at t=0) ----
  for (int e = tid; e < 2 * 16 * 16 * 8; e += NTHREADS)
    (&sh.h[0][0][0][0])[e] = (__bf16)0.f;
  f32x4 cst = {0.f, 0.f, 0.f, 0.f};   // cell state: rows 16w+4q+0..3, col n16
  __syncthreads();

  for (int c = 0; c < NCHUNK; ++c) {
    // ---- A) parallel waits, ONE barrier: tid0 waits upstream chunk c ready;
    //         tid64 waits ring slot for hist(c-1) free (backpressure) ----
    if (lyr > 0 && tid == 0) {
      for (int it = 0; it < SPIN_LIMIT && afl_load(flag_up) < c + 1; ++it)
        __builtin_amdgcn_s_sleep(2);
    }
    if (lyr < 2 && c >= RSLOT + 1 && tid == 64) {
      for (int it = 0; it < SPIN_LIMIT && afl_load(cons_my) < c - RSLOT; ++it)
        __builtin_amdgcn_s_sleep(2);
    }
    __syncthreads();

    // ---- B) issue flush of hist(c-1) -> ring slot (atomic stores to IC);
    //         drained by the post-prologue barrier ----
    if (lyr < 2 && c > 0) {
      u64* dst = mybuf + (size_t)((c - 1) % RSLOT) * CH_U64;
      const u64* hsrc = (const u64*)&sh.hist[0][0][0][0];
      #pragma unroll
      for (int it = 0; it < 4; ++it) {
        const int j = tid + it * NTHREADS;     // 2048 u64 jobs, verbatim copy
        adat_store(dst + j, hsrc[j]);
      }
    }

    // ---- C) prologue: xg(c) into registers (C-init layout) ----
    f32x4 xg[TC][4];
    #pragma unroll
    for (int s = 0; s < TC; ++s)
      #pragma unroll
      for (int i = 0; i < 4; ++i) xg[s][i] = biasv[i];

    if (lyr == 0) {
      #pragma unroll
      for (int s = 0; s < TC; ++s) {
        bf16x8 bfrag = zero_bf16x8();
        if (q == 0)      // k = q*8+j < 8 only in quad 0; weights zero-padded past 8
          bfrag = load8_f32_bf16(x + ((size_t)(bg + n16) * T_LEN + c * TC + s) * F_IN_D);
        #pragma unroll
        for (int i = 0; i < 4; ++i)
          xg[s][i] = __builtin_amdgcn_mfma_f32_16x16x32_bf16(wih0f[i], bfrag, xg[s][i], 0, 0, 0);
      }
    } else {
      const u64* src = upbuf + (size_t)(c % RSLOT) * CH_U64;
      #pragma unroll
      for (int kc = 0; kc < 4; ++kc) {
        bf16x8 wf[4];
        #pragma unroll
        for (int i = 0; i < 4; ++i)
          wf[i] = *(const bf16x8*)(ws + WS_WIH12 +
              ((((size_t)(lyr - 1) * 32 + (w + 8 * i)) * 4 + kc) * 64 + l) * 8);
        #pragma unroll
        for (int s = 0; s < TC; ++s) {
          // bf16x8 at elem off (((s*16 + kc*4+q)*16)+n16)*8 = 2 consecutive u64
          const int ui = ((s * 16 + kc * 4 + q) * 16 + n16) * 2;
          union { u64 u[2]; bf16x8 v; } cvt;
          cvt.u[0] = adat_load(src + ui);
          cvt.u[1] = adat_load(src + ui + 1);
          #pragma unroll
          for (int i = 0; i < 4; ++i)
            xg[s][i] = __builtin_amdgcn_mfma_f32_16x16x32_bf16(wf[i], cvt.v, xg[s][i], 0, 0, 0);
        }
      }
    }

    // barrier drains vmcnt(0)+lgkmcnt(0) for ALL threads (compiler emits full
    // waitcnt before s_barrier): flush atomics complete at IC, slot-c reads
    // done, hist ds_reads done. Flag publishes after it are globally ordered.
    __syncthreads();
    if (lyr < 2 && c > 0 && tid == 0) afl_store(flag_my, c);
    if (lyr > 0 && tid == 0) afl_store(cons_up, c + 1);

    // ---- D) TC recurrence steps: MFMA + in-register gates, ONE barrier ----
    #pragma unroll
    for (int s = 0; s < TC; ++s) {
      const int cur = s & 1, nxt = cur ^ 1;
      f32x4 acc[4];
      #pragma unroll
      for (int k = 0; k < 4; ++k) acc[k] = xg[s][k];
      #pragma unroll
      for (int kc = 0; kc < 4; ++kc) {
        // contiguous 1KB wave read: lane (q,n16) -> h[cur][kc*4+q][n16][0..8)
        const bf16x8 bfrag = *(const bf16x8*)&sh.h[cur][kc * 4 + q][n16][0];
        #pragma unroll
        for (int k = 0; k < 4; ++k)
          acc[k] = __builtin_amdgcn_mfma_f32_16x16x32_bf16(whhf[k][kc], bfrag, acc[k], 0, 0, 0);
      }
      // in-register gates: acc[0..3][r] = i,f,g,o for j=16w+4q+r, batch n16
      bf16x4 hb;
      #pragma unroll
      for (int r = 0; r < 4; ++r) {
        const float gi = sigf(acc[0][r]);
        const float gf = sigf(acc[1][r]);
        const float gg = tanh_fast(acc[2][r]);
        const float go = sigf(acc[3][r]);
        cst[r] = gf * cst[r] + gi * gg;
        hb[r]  = (__bf16)(go * tanh_fast(cst[r]));
      }
      *(bf16x4*)&sh.h[nxt][kg_w][n16][sub] = hb;
      if (lyr < 2) *(bf16x4*)&sh.hist[s][kg_w][n16][sub] = hb;
      __syncthreads();
    }
  }

  // ---- final flush of hist(NCHUNK-1) + terminal flag ----
  if (lyr < 2) {
    const int m = NCHUNK - 1;
    if (tid == 0) {
      for (int it = 0; it < SPIN_LIMIT && afl_load(cons_my) < m - RSLOT + 1; ++it)
        __builtin_amdgcn_s_sleep(2);
    }
    __syncthreads();
    u64* dst = mybuf + (size_t)(m % RSLOT) * CH_U64;
    const u64* hsrc = (const u64*)&sh.hist[0][0][0][0];
    #pragma unroll
    for (int it = 0; it < 4; ++it) {
      const int j = tid + it * NTHREADS;
      adat_store(dst + j, hsrc[j]);
    }
    __syncthreads();   // drains vmcnt(0): data at IC before flag
    if (tid == 0) afl_store(flag_my, NCHUNK);
  }

  // ---- FC head: layer-2 blocks; t=511 (s=3) wrote parity 0 ----
  if (lyr == 2) {
    for (int j = tid; j < BBATCH * H_DIM; j += NTHREADS) {
      const int b = j >> 7, i = j & 127;
      float a = fc1b[i];
      #pragma unroll 8
      for (int k = 0; k < H_DIM; ++k)
        a += (float)sh.h[0][k >> 3][b][k & 7] * fc1w[i * H_DIM + k];
      sh.z[b][i] = fmaxf(a, 0.f);
    }
    __syncthreads();
    if (tid < BBATCH * OUT_DIM) {
      const int b = tid / OUT_DIM, o = tid % OUT_DIM;
      float a = fc2b[o];
      for (int k = 0; k < H_DIM; ++k)
        a += sh.z[b][k] * fc2w[o * H_DIM + k];
      out[(size_t)(bg + b) * OUT_DIM + o] = a;
    }
  }
}

extern "C" void kernel_launch(void* const* d_in, const int* in_sizes, int n_in,
                              void* d_out, int out_size, void* d_ws, size_t ws_size,
                              hipStream_t stream) {
  const float* x    = (const float*)d_in[0];
  const float* wih0 = (const float*)d_in[1];
  const float* whh0 = (const float*)d_in[2];
  const float* bih0 = (const float*)d_in[3];
  const float* bhh0 = (const float*)d_in[4];
  const float* wih1 = (const float*)d_in[5];
  const float* whh1 = (const float*)d_in[6];
  const float* bih1 = (const float*)d_in[7];
  const float* bhh1 = (const float*)d_in[8];
  const float* wih2 = (const float*)d_in[9];
  const float* whh2 = (const float*)d_in[10];
  const float* bih2 = (const float*)d_in[11];
  const float* bhh2 = (const float*)d_in[12];
  const float* fc1w = (const float*)d_in[13];
  const float* fc1b = (const float*)d_in[14];
  const float* fc2w = (const float*)d_in[15];
  const float* fc2b = (const float*)d_in[16];
  float* out  = (float*)d_out;
  __bf16* ws  = (__bf16*)d_ws;   // ~33.7 MB used (weights + flags + 32 MB ring)

  prep_kernel<<<dim3(175), dim3(256), 0, stream>>>(
      wih0, whh0, bih0, bhh0, wih1, whh1, bih1, bhh1,
      wih2, whh2, bih2, bhh2, ws);
  lstm_kernel<<<dim3(3 * NGRP), dim3(NTHREADS), 0, stream>>>(
      x, fc1w, fc1b, fc2w, fc2b, out, ws);
}

// Round 6
// 1083.065 us; speedup vs baseline: 1.5884x; 1.0747x over previous
//
#include <hip/hip_runtime.h>

#define B_TOT   512
#define T_LEN   512
#define F_IN_D  8
#define H_DIM   128
#define OUT_DIM 7
#define TC      4                 // timesteps per chunk (xg register granularity)
#define NCHUNK  (T_LEN / TC)      // 128
#define RSLOT   32                // ring slots per layer boundary
#define BBATCH  16                // batch rows per block (full MFMA N)
#define NGRP    (B_TOT / BBATCH)  // 32 groups
#define NTHREADS 512              // 8 waves
#define SPIN_LIMIT (1 << 18)      // bounded waits: fail-visible, never hang

typedef __bf16 bf16x8 __attribute__((ext_vector_type(8)));
typedef __bf16 bf16x4 __attribute__((ext_vector_type(4)));
typedef float  f32x4  __attribute__((ext_vector_type(4)));
typedef unsigned long long u64;

// ---- workspace layout (bf16 element offsets) ----
#define WS_WHH   0                     // [3][32][4][64][8] = 196608
#define WS_WIH12 196608                // [2][32][4][64][8] = 131072
#define WS_WIH0  327680                // [32][64][8] = 16384 (k>=8 zero-padded)
#define WS_BIAS  344064                // float[3][512] combined b_ih+b_hh
#define WS_FLAGS 347136                // int[2][32] flags, then int[2][32] consumed
#define WS_BUF   347648                // [2][32] pair ring buffers
#define CH_ELEMS   (TC * BBATCH * H_DIM)   // 8192 bf16 per chunk (16 KB)
#define CH_U64     (CH_ELEMS / 4)          // 2048 u64 per chunk
#define PAIR_ELEMS (RSLOT * CH_ELEMS)      // 262144 (512 KiB per pair)

// h layout [kgroup][batch][8]: element (batch b, hdim k) at [k>>3][b][k&7].
// Step B-frag read (lane q,n16 needs k in [kc*32+q*8,+8), col n16) is a
// CONTIGUOUS 1KB wave read -> zero bank conflicts. Ring slots + the LDS ring
// mirror use the same layout: flush is a verbatim 16KB copy, staged reads are
// contiguous.
struct __align__(16) SharedMem {
  __bf16 h[2][16][16][8];     // [step parity][kgroup][batch][k&7]  (8 KB)
  __bf16 hist[TC][16][16][8]; // chunk h history, ring-slot layout  (16 KB)
  u64    ring[CH_U64];        // LDS mirror of upstream ring slot   (16 KB)
  float  z[16][H_DIM];        // fc1 output (layer-2 blocks only)   (8 KB)
};

__device__ __forceinline__ float sigf(float x) {
  return __builtin_amdgcn_rcpf(1.f + __expf(-x));
}
__device__ __forceinline__ float tanh_fast(float x) {
  x = fminf(fmaxf(x, -15.f), 15.f);
  float e = __expf(2.f * x);
  return (e - 1.f) * __builtin_amdgcn_rcpf(e + 1.f);
}
__device__ __forceinline__ bf16x8 load8_f32_bf16(const float* p) {
  const f32x4 a = *(const f32x4*)p;
  const f32x4 b = *(const f32x4*)(p + 4);
  bf16x8 r;
  #pragma unroll
  for (int j = 0; j < 4; ++j) { r[j] = (__bf16)a[j]; r[4 + j] = (__bf16)b[j]; }
  return r;
}
__device__ __forceinline__ bf16x8 zero_bf16x8() {
  bf16x8 r;
  #pragma unroll
  for (int j = 0; j < 8; ++j) r[j] = (__bf16)0.f;
  return r;
}
// All cross-block traffic is agent-scope RELAXED atomics -> coherent at the
// IC by construction (no wbl2/inv cache maintenance; R6 measured win).
// Ordering: the phase-C __syncthreads drains each thread's vmcnt(0)
// (compiler-guaranteed before s_barrier), so data atomics are complete at the
// coherence point before any flag atomic issued after it.
__device__ __forceinline__ int afl_load(int* p) {
  return __hip_atomic_load(p, __ATOMIC_RELAXED, __HIP_MEMORY_SCOPE_AGENT);
}
__device__ __forceinline__ void afl_store(int* p, int v) {
  __hip_atomic_store(p, v, __ATOMIC_RELAXED, __HIP_MEMORY_SCOPE_AGENT);
}
__device__ __forceinline__ u64 adat_load(const u64* p) {
  return __hip_atomic_load(p, __ATOMIC_RELAXED, __HIP_MEMORY_SCOPE_AGENT);
}
__device__ __forceinline__ void adat_store(u64* p, u64 v) {
  __hip_atomic_store(p, v, __ATOMIC_RELAXED, __HIP_MEMORY_SCOPE_AGENT);
}

// ---- prep: pack weights into frag order (bf16), combine biases, zero flags ----
__global__ void prep_kernel(const float* __restrict__ wih0, const float* __restrict__ whh0,
                            const float* __restrict__ bih0, const float* __restrict__ bhh0,
                            const float* __restrict__ wih1, const float* __restrict__ whh1,
                            const float* __restrict__ bih1, const float* __restrict__ bhh1,
                            const float* __restrict__ wih2, const float* __restrict__ whh2,
                            const float* __restrict__ bih2, const float* __restrict__ bhh2,
                            __bf16* __restrict__ ws)
{
  const float* WHH[3] = {whh0, whh1, whh2};
  const float* WIH[3] = {wih0, wih1, wih2};
  const float* BIH[3] = {bih0, bih1, bih2};
  const float* BHH[3] = {bhh0, bhh1, bhh2};
  const int NWHH = 3 * 32 * 4 * 64;   // 24576
  const int NWIH = 2 * 32 * 4 * 64;   // 16384
  const int NW0  = 32 * 64;           // 2048
  const int NBIA = 3 * 512;           // 1536
  const int NFLG = 128;               // flags + consumed
  const int TOTAL = NWHH + NWIH + NW0 + NBIA + NFLG;
  for (int idx = blockIdx.x * blockDim.x + threadIdx.x; idx < TOTAL;
       idx += gridDim.x * blockDim.x) {
    if (idx < NWHH) {
      const int lyr = idx >> 13, rem = idx & 8191;
      const int mt = rem >> 8, kc = (rem >> 6) & 3, lane = rem & 63;
      const int row = 16 * mt + (lane & 15);
      const int k0  = kc * 32 + (lane >> 4) * 8;
      const float* src = WHH[lyr] + row * H_DIM + k0;
      __bf16* dst = ws + WS_WHH + (size_t)idx * 8;
      #pragma unroll
      for (int j = 0; j < 8; ++j) dst[j] = (__bf16)src[j];
    } else if (idx < NWHH + NWIH) {
      const int i2 = idx - NWHH;
      const int lyr = (i2 >> 13) + 1, rem = i2 & 8191;
      const int mt = rem >> 8, kc = (rem >> 6) & 3, lane = rem & 63;
      const int row = 16 * mt + (lane & 15);
      const int k0  = kc * 32 + (lane >> 4) * 8;
      const float* src = WIH[lyr] + row * H_DIM + k0;
      __bf16* dst = ws + WS_WIH12 + (size_t)i2 * 8;
      #pragma unroll
      for (int j = 0; j < 8; ++j) dst[j] = (__bf16)src[j];
    } else if (idx < NWHH + NWIH + NW0) {
      const int i3 = idx - NWHH - NWIH;
      const int mt = i3 >> 6, lane = i3 & 63;
      const int row = 16 * mt + (lane & 15);
      const int k0  = (lane >> 4) * 8;
      __bf16* dst = ws + WS_WIH0 + (size_t)i3 * 8;
      #pragma unroll
      for (int j = 0; j < 8; ++j) {
        const int k = k0 + j;
        dst[j] = (k < F_IN_D) ? (__bf16)WIH[0][row * F_IN_D + k] : (__bf16)0.f;
      }
    } else if (idx < NWHH + NWIH + NW0 + NBIA) {
      const int i4 = idx - NWHH - NWIH - NW0;
      float* fb = (float*)(ws + WS_BIAS);
      fb[i4] = BIH[i4 >> 9][i4 & 511] + BHH[i4 >> 9][i4 & 511];
    } else {
      const int i5 = idx - NWHH - NWIH - NW0 - NBIA;
      ((int*)(ws + WS_FLAGS))[i5] = 0;
    }
  }
}

// R7: R6 + LDS-staged ring reads. R6's prologue had EVERY wave atomic-loading
// the same 16KB chunk (8x redundant = 128KB of IC-latency atomics per block
// per chunk -> the dominant stall). Now phase B stages the chunk ONCE
// (4 coalesced u64 atomic loads/thread -> ds_write), phase C's single barrier
// drains stage writes + flush stores, and the prologue reads B-fragments from
// LDS (contiguous 1KB wave reads, conflict-free). Handshake protocol is
// byte-identical to the passing R6. All spins bounded.
__global__ __launch_bounds__(NTHREADS, 2)
void lstm_kernel(const float* __restrict__ x,
                 const float* __restrict__ fc1w, const float* __restrict__ fc1b,
                 const float* __restrict__ fc2w, const float* __restrict__ fc2b,
                 float* __restrict__ out, __bf16* __restrict__ ws)
{
  __shared__ SharedMem sh;
  const int tid = threadIdx.x;
  const int w   = tid >> 6;   // wave 0..7
  const int l   = tid & 63;   // lane
  const int q   = l >> 4;     // quad 0..3
  const int n16 = l & 15;     // MFMA col = batch row within group
  const int lyr = blockIdx.x >> 5;   // 0..2
  const int g   = blockIdx.x & 31;   // batch group
  const int bg  = g * BBATCH;
  const int kg_w = 2 * w + (q >> 1); // kgroup this thread's h-rows land in
  const int sub  = (q & 1) * 4;      // sub-offset within the 8-elem kgroup

  int* flags = (int*)(ws + WS_FLAGS);
  int* cons  = flags + 64;
  const int myidx = (lyr < 2) ? lyr * NGRP + g : 0;
  const int upidx = (lyr > 0) ? (lyr - 1) * NGRP + g : 0;
  int* flag_my = &flags[myidx];
  int* flag_up = &flags[upidx];
  int* cons_my = &cons[myidx];
  int* cons_up = &cons[upidx];
  u64*       mybuf = (u64*)(ws + WS_BUF + (size_t)myidx * PAIR_ELEMS);
  const u64* upbuf = (const u64*)(ws + WS_BUF + (size_t)upidx * PAIR_ELEMS);

  // ---- resident whh fragments + combined bias ----
  bf16x8 whhf[4][4];
  f32x4  biasv[4];
  #pragma unroll
  for (int i = 0; i < 4; ++i) {
    #pragma unroll
    for (int kc = 0; kc < 4; ++kc)
      whhf[i][kc] = *(const bf16x8*)(
          ws + WS_WHH + ((((size_t)lyr * 32 + (w + 8 * i)) * 4 + kc) * 64 + l) * 8);
    const float* fb = (const float*)(ws + WS_BIAS) + lyr * 512 + 16 * (w + 8 * i) + 4 * q;
    biasv[i] = *(const f32x4*)fb;
  }
  bf16x8 wih0f[4];
  if (lyr == 0) {
    #pragma unroll
    for (int i = 0; i < 4; ++i)
      wih0f[i] = *(const bf16x8*)(ws + WS_WIH0 + ((size_t)(w + 8 * i) * 64 + l) * 8);
  }

  // ---- zero initial h (parity 0 read at t=0) ----
  for (int e = tid; e < 2 * 16 * 16 * 8; e += NTHREADS)
    (&sh.h[0][0][0][0])[e] = (__bf16)0.f;
  f32x4 cst = {0.f, 0.f, 0.f, 0.f};   // cell state: rows 16w+4q+0..3, col n16
  __syncthreads();

  for (int c = 0; c < NCHUNK; ++c) {
    // ---- A) parallel waits, ONE barrier: tid0 waits upstream chunk c ready;
    //         tid64 waits ring slot for hist(c-1) free (backpressure) ----
    if (lyr > 0 && tid == 0) {
      for (int it = 0; it < SPIN_LIMIT && afl_load(flag_up) < c + 1; ++it)
        __builtin_amdgcn_s_sleep(1);
    }
    if (lyr < 2 && c >= RSLOT + 1 && tid == 64) {
      for (int it = 0; it < SPIN_LIMIT && afl_load(cons_my) < c - RSLOT; ++it)
        __builtin_amdgcn_s_sleep(1);
    }
    __syncthreads();

    // ---- B) stage upstream slot c -> LDS ring (ONCE: 4 u64/thread), and
    //         issue flush of hist(c-1) -> my ring slot ----
    if (lyr > 0) {
      const u64* src = upbuf + (size_t)(c % RSLOT) * CH_U64;
      #pragma unroll
      for (int it = 0; it < 4; ++it) {
        const int j = tid + it * NTHREADS;     // coalesced 8B x 64 lanes
        sh.ring[j] = adat_load(src + j);       // vmcnt wait folded before ds_write
      }
    }
    if (lyr < 2 && c > 0) {
      u64* dst = mybuf + (size_t)((c - 1) % RSLOT) * CH_U64;
      const u64* hsrc = (const u64*)&sh.hist[0][0][0][0];
      #pragma unroll
      for (int it = 0; it < 4; ++it) {
        const int j = tid + it * NTHREADS;     // 2048 u64 jobs, verbatim copy
        adat_store(dst + j, hsrc[j]);
      }
    }

    // ---- C) barrier drains vmcnt(0)+lgkmcnt(0) for ALL threads: stage
    //         ds_writes visible, flush stores complete at IC, slot-c reads
    //         done. Flag publishes after it are globally ordered. ----
    __syncthreads();
    if (lyr < 2 && c > 0 && tid == 0) afl_store(flag_my, c);
    if (lyr > 0 && tid == 0) afl_store(cons_up, c + 1);

    // ---- P) prologue: xg(c) into registers (C-init layout) ----
    f32x4 xg[TC][4];
    #pragma unroll
    for (int s = 0; s < TC; ++s)
      #pragma unroll
      for (int i = 0; i < 4; ++i) xg[s][i] = biasv[i];

    if (lyr == 0) {
      #pragma unroll
      for (int s = 0; s < TC; ++s) {
        bf16x8 bfrag = zero_bf16x8();
        if (q == 0)      // k = q*8+j < 8 only in quad 0; weights zero-padded past 8
          bfrag = load8_f32_bf16(x + ((size_t)(bg + n16) * T_LEN + c * TC + s) * F_IN_D);
        #pragma unroll
        for (int i = 0; i < 4; ++i)
          xg[s][i] = __builtin_amdgcn_mfma_f32_16x16x32_bf16(wih0f[i], bfrag, xg[s][i], 0, 0, 0);
      }
    } else {
      const __bf16* rb = (const __bf16*)sh.ring;
      #pragma unroll
      for (int kc = 0; kc < 4; ++kc) {
        bf16x8 wf[4];
        #pragma unroll
        for (int i = 0; i < 4; ++i)
          wf[i] = *(const bf16x8*)(ws + WS_WIH12 +
              ((((size_t)(lyr - 1) * 32 + (w + 8 * i)) * 4 + kc) * 64 + l) * 8);
        #pragma unroll
        for (int s = 0; s < TC; ++s) {
          // contiguous 1KB wave read: lane (q,n16) -> ring[s][kc*4+q][n16][0..8)
          const bf16x8 bfrag =
              *(const bf16x8*)&rb[((s * 16 + kc * 4 + q) * 16 + n16) * 8];
          #pragma unroll
          for (int i = 0; i < 4; ++i)
            xg[s][i] = __builtin_amdgcn_mfma_f32_16x16x32_bf16(wf[i], bfrag, xg[s][i], 0, 0, 0);
        }
      }
    }

    // ---- D) TC recurrence steps: MFMA + in-register gates, ONE barrier ----
    #pragma unroll
    for (int s = 0; s < TC; ++s) {
      const int cur = s & 1, nxt = cur ^ 1;
      f32x4 acc[4];
      #pragma unroll
      for (int k = 0; k < 4; ++k) acc[k] = xg[s][k];
      #pragma unroll
      for (int kc = 0; kc < 4; ++kc) {
        // contiguous 1KB wave read: lane (q,n16) -> h[cur][kc*4+q][n16][0..8)
        const bf16x8 bfrag = *(const bf16x8*)&sh.h[cur][kc * 4 + q][n16][0];
        #pragma unroll
        for (int k = 0; k < 4; ++k)
          acc[k] = __builtin_amdgcn_mfma_f32_16x16x32_bf16(whhf[k][kc], bfrag, acc[k], 0, 0, 0);
      }
      // in-register gates: acc[0..3][r] = i,f,g,o for j=16w+4q+r, batch n16
      bf16x4 hb;
      #pragma unroll
      for (int r = 0; r < 4; ++r) {
        const float gi = sigf(acc[0][r]);
        const float gf = sigf(acc[1][r]);
        const float gg = tanh_fast(acc[2][r]);
        const float go = sigf(acc[3][r]);
        cst[r] = gf * cst[r] + gi * gg;
        hb[r]  = (__bf16)(go * tanh_fast(cst[r]));
      }
      *(bf16x4*)&sh.h[nxt][kg_w][n16][sub] = hb;
      if (lyr < 2) *(bf16x4*)&sh.hist[s][kg_w][n16][sub] = hb;
      __syncthreads();
    }
  }

  // ---- final flush of hist(NCHUNK-1) + terminal flag ----
  if (lyr < 2) {
    const int m = NCHUNK - 1;
    if (tid == 0) {
      for (int it = 0; it < SPIN_LIMIT && afl_load(cons_my) < m - RSLOT + 1; ++it)
        __builtin_amdgcn_s_sleep(1);
    }
    __syncthreads();
    u64* dst = mybuf + (size_t)(m % RSLOT) * CH_U64;
    const u64* hsrc = (const u64*)&sh.hist[0][0][0][0];
    #pragma unroll
    for (int it = 0; it < 4; ++it) {
      const int j = tid + it * NTHREADS;
      adat_store(dst + j, hsrc[j]);
    }
    __syncthreads();   // drains vmcnt(0): data at IC before flag
    if (tid == 0) afl_store(flag_my, NCHUNK);
  }

  // ---- FC head: layer-2 blocks; t=511 (s=3) wrote parity 0 ----
  if (lyr == 2) {
    for (int j = tid; j < BBATCH * H_DIM; j += NTHREADS) {
      const int b = j >> 7, i = j & 127;
      float a = fc1b[i];
      #pragma unroll 8
      for (int k = 0; k < H_DIM; ++k)
        a += (float)sh.h[0][k >> 3][b][k & 7] * fc1w[i * H_DIM + k];
      sh.z[b][i] = fmaxf(a, 0.f);
    }
    __syncthreads();
    if (tid < BBATCH * OUT_DIM) {
      const int b = tid / OUT_DIM, o = tid % OUT_DIM;
      float a = fc2b[o];
      for (int k = 0; k < H_DIM; ++k)
        a += sh.z[b][k] * fc2w[o * H_DIM + k];
      out[(size_t)(bg + b) * OUT_DIM + o] = a;
    }
  }
}

extern "C" void kernel_launch(void* const* d_in, const int* in_sizes, int n_in,
                              void* d_out, int out_size, void* d_ws, size_t ws_size,
                              hipStream_t stream) {
  const float* x    = (const float*)d_in[0];
  const float* wih0 = (const float*)d_in[1];
  const float* whh0 = (const float*)d_in[2];
  const float* bih0 = (const float*)d_in[3];
  const float* bhh0 = (const float*)d_in[4];
  const float* wih1 = (const float*)d_in[5];
  const float* whh1 = (const float*)d_in[6];
  const float* bih1 = (const float*)d_in[7];
  const float* bhh1 = (const float*)d_in[8];
  const float* wih2 = (const float*)d_in[9];
  const float* whh2 = (const float*)d_in[10];
  const float* bih2 = (const float*)d_in[11];
  const float* bhh2 = (const float*)d_in[12];
  const float* fc1w = (const float*)d_in[13];
  const float* fc1b = (const float*)d_in[14];
  const float* fc2w = (const float*)d_in[15];
  const float* fc2b = (const float*)d_in[16];
  float* out  = (float*)d_out;
  __bf16* ws  = (__bf16*)d_ws;   // ~33.7 MB used (weights + flags + 32 MB ring)

  prep_kernel<<<dim3(175), dim3(256), 0, stream>>>(
      wih0, whh0, bih0, bhh0, wih1, whh1, bih1, bhh1,
      wih2, whh2, bih2, bhh2, ws);
  lstm_kernel<<<dim3(3 * NGRP), dim3(NTHREADS), 0, stream>>>(
      x, fc1w, fc1b, fc2w, fc2b, out, ws);
}